// Round 14
// baseline (185.427 us; speedup 1.0000x reference)
//
#include <hip/hip_runtime.h>

// ModulatedConv2d: B=16, IN=512, OUT=512, STYLE=512, K=3, H=W=32
// out[b,o] = scale[b,o] * conv2d(x[b,i]*s[b,i], W[o,i])   (shared weights!)
// Conv = one implicit GEMM: M=512 out-ch, N=16384 (b,px), K=9x512.
// x staged as zero-padded NHWC bf16 -> no boundary masking.
//
// R12: 128x128 4w reg-staged dbuf: 91.6us. R16: 1w/SIMD: 133us.
// R13/14: B-direct: ~161us. R15: raw lgkm barrier = R12. R18: 90.3us.
// R17: 128x256 8w 2(wm)x2(wn)x2(kg) dbuf 1blk/CU: 86.5us.
// R19: source-order interleave: 85.0. R20: +SGB read/MFMA pins: 81.8
//      (MfmaUtil 39%). R21: writes-under-MFMA: 82.5 NEUTRAL.
// R22 (this): staging via global_load_lds DMA (m151: DMA 874 vs
//      reg-staging 646 TF at this tile class). Removes 48 ds_write issues
//      + 12 staged loads + COMMIT chain per CU-step; LDS writes land async
//      during compute. R5's DMA race explained: DMA completion is vmcnt-
//      tracked -> SYNC now drains vmcnt(0)+lgkmcnt(0) (cheap, loads are a
//      full phase old; R15 proved drain ~free). Swizzle kept via rule #21:
//      LINEAR LDS dest + PRE-SWIZZLED per-lane global source (lane l
//      fetches chunk (l&7)^(l>>3) of its row -- same 128B segment,
//      coalescing intact). Geometry/kg-split/SGB pins/epilogue unchanged.
//      Predict: conv 66-74us, MfmaUtil 44-50%, VGPR ~90. Neutral =>
//      family floor ~82us.

#define BATCH   16
#define CIN     512
#define COUT    512
#define IMG     32
#define PAD_IMG 34

static constexpr float AFF_SCALE = 0.044194173824159216f;  // 1/sqrt(512)
static constexpr float W_SCALE   = 0.014731391274719739f;  // 1/sqrt(512*9)

typedef __bf16 bf16x8 __attribute__((ext_vector_type(8)));
typedef float  f32x4  __attribute__((ext_vector_type(4)));

__device__ inline unsigned short f2bf(float f) {
    union { float f; unsigned int u; } v; v.f = f;
    unsigned int u = v.u;
    unsigned int r = (u + 0x7FFFu + ((u >> 16) & 1u)) >> 16;
    return (unsigned short)r;
}

__device__ inline float waveReduceSum(float v) {
    #pragma unroll
    for (int off = 32; off > 0; off >>= 1) v += __shfl_xor(v, off, 64);
    return v;
}

// global->LDS DMA, 16B/lane. LDS dest = wave-uniform base + lane*16.
__device__ inline void gload16(const unsigned short* g, unsigned short* l) {
    __builtin_amdgcn_global_load_lds(
        (const __attribute__((address_space(1))) void*)g,
        (__attribute__((address_space(3))) void*)l, 16, 0, 0);
}

// ---- kernel 1: fused prep ----
__global__ void prep1(const float* __restrict__ cw,
                      const float* __restrict__ style,
                      const float* __restrict__ aw,
                      const float* __restrict__ ab,
                      unsigned short* __restrict__ w_t,
                      float* __restrict__ wsq,
                      float* __restrict__ s_out) {
    const int tid = threadIdx.x;
    if (blockIdx.x < 512) {
        __shared__ float wl[4608];                    // 512 idx x 9
        const float* src = cw + (size_t)blockIdx.x * 4608;
        for (int j = tid; j < 1152; j += 256)         // float4 loads
            *(float4*)(wl + j * 4) = *(const float4*)(src + j * 4);
        __syncthreads();
        const int idx0 = blockIdx.x * 512 + tid * 2;  // two consecutive idx
        const int base = tid * 18;
        float acc0 = 0.f, acc1 = 0.f;
        #pragma unroll
        for (int e = 0; e < 9; ++e) {
            float v0 = wl[base + e];
            float v1 = wl[base + 9 + e];
            acc0 += v0 * v0;
            acc1 += v1 * v1;
            unsigned int pk = (unsigned)f2bf(v0) | ((unsigned)f2bf(v1) << 16);
            *(unsigned int*)(w_t + (size_t)e * (COUT * CIN) + idx0) = pk;
        }
        *(float2*)(wsq + idx0) = make_float2(acc0, acc1);
    } else {
        const int q = blockIdx.x - 512;               // 0..2047
        const int b = q >> 7;
        const int i = (q & 127) * 4 + (tid >> 6);
        const int lane = tid & 63;
        const float4* a4 = (const float4*)(aw + (size_t)i * 512);
        const float4* s4 = (const float4*)(style + (size_t)b * 512);
        float sum = 0.f;
        #pragma unroll
        for (int r = 0; r < 2; ++r) {
            float4 av = a4[lane * 2 + r];
            float4 sv = s4[lane * 2 + r];
            sum += av.x * sv.x + av.y * sv.y + av.z * sv.z + av.w * sv.w;
        }
        sum = waveReduceSum(sum);
        if (lane == 0)
            s_out[b * 512 + i] = sum * AFF_SCALE + ab[i] + 1.0f;
    }
}

// ---- kernel 2: fused xpad + scale ----
__global__ void prep2(const float* __restrict__ x,
                      const float* __restrict__ s_in,
                      const float* __restrict__ wsq,
                      unsigned short* __restrict__ xpad,
                      float* __restrict__ scl) {
    const int tid = threadIdx.x;
    if (blockIdx.x >= 4352) {
        const int q = blockIdx.x - 4352;              // 0..2047
        const int b = q >> 7;                         // 0..15
        const int o = (q & 127) * 4 + (tid >> 6);     // 0..511
        const int lane = tid & 63;
        const float4* w4p = (const float4*)(wsq + (size_t)o * 512);
        const float4* s4p = (const float4*)(s_in + (size_t)b * 512);
        float sum = 0.f;
        #pragma unroll
        for (int r = 0; r < 2; ++r) {
            float4 wv = w4p[lane * 2 + r];
            float4 sv = s4p[lane * 2 + r];
            sum += sv.x * sv.x * wv.x + sv.y * sv.y * wv.y
                 + sv.z * sv.z * wv.z + sv.w * sv.w * wv.w;
        }
        sum = waveReduceSum(sum);
        if (lane == 0)
            scl[b * 512 + o] = W_SCALE * rsqrtf(W_SCALE * W_SCALE * sum + 1e-8f);
        return;
    }
    const int c0   = blockIdx.x & 7;                  // *64 channels
    const int rest = blockIdx.x >> 3;                 // 0..543
    const int hh   = rest % 34;
    const int b    = rest / 34;
    const int c0b  = c0 * 64;
    unsigned short* rowbase = xpad + (((size_t)b * PAD_IMG + hh) * PAD_IMG) * 512;

    if (hh == 0 || hh == PAD_IMG - 1) {
        for (int j = tid; j < 34 * 32; j += 256) {
            int ww = j >> 5, cp = (j & 31) * 2;
            *(unsigned int*)(rowbase + (size_t)ww * 512 + c0b + cp) = 0u;
        }
        return;
    }

    __shared__ float t[64][33];
    const int h = hh - 1;
    #pragma unroll
    for (int r = 0; r < 2; ++r) {
        const int f   = r * 256 + tid;                // 0..511
        const int chl = f >> 3;                       // 0..63
        const int w4  = (f & 7) * 4;
        float4 xv = *(const float4*)(
            x + (((size_t)b * 512 + c0b + chl) * IMG + h) * IMG + w4);
        const float sv = s_in[b * 512 + c0b + chl];
        t[chl][w4 + 0] = xv.x * sv;
        t[chl][w4 + 1] = xv.y * sv;
        t[chl][w4 + 2] = xv.z * sv;
        t[chl][w4 + 3] = xv.w * sv;
    }
    __syncthreads();
    {
        const int p  = tid >> 3;
        const int cc = (tid & 7) * 8;
        unsigned short* dst = rowbase + (size_t)(p + 1) * 512 + c0b + cc;
        uint4 pk;
        pk.x = (unsigned)f2bf(t[cc + 0][p]) | ((unsigned)f2bf(t[cc + 1][p]) << 16);
        pk.y = (unsigned)f2bf(t[cc + 2][p]) | ((unsigned)f2bf(t[cc + 3][p]) << 16);
        pk.z = (unsigned)f2bf(t[cc + 4][p]) | ((unsigned)f2bf(t[cc + 5][p]) << 16);
        pk.w = (unsigned)f2bf(t[cc + 6][p]) | ((unsigned)f2bf(t[cc + 7][p]) << 16);
        *(uint4*)dst = pk;
    }
    if (tid < 64) {
        int ww = (tid >> 5) ? (PAD_IMG - 1) : 0;
        int cp = (tid & 31) * 2;
        *(unsigned int*)(rowbase + (size_t)ww * 512 + c0b + cp) = 0u;
    }
}

// ---- kernel 3: implicit-GEMM conv, 128x256 block, 8 waves, BK=64 ----
// Waves: wm=(wid>>1)&1, wn=wid&1, kg=wid>>2. Wave tile 64x128 x k-half.
// DMA-staged dbuf: 6 global_load_lds per wave per step (A 2 + B 4),
// issued at phase top for buf^1, drained by vmcnt(0) at phase end.
// R20 SGB read/MFMA interleave; one barrier per step.

// SYNC drains DMA (vmcnt) + ds reads (lgkm) then barriers.
#define SYNC() do {                                                           \
    asm volatile("s_waitcnt vmcnt(0) lgkmcnt(0)" ::: "memory");               \
    __builtin_amdgcn_s_barrier();                                             \
    __builtin_amdgcn_sched_barrier(0);                                        \
} while (0)

// DMA one step's tiles into (AT, BT). Per wave: 2 A + 4 B instructions.
#define DMASTEP(stp, AT, BT) do {                                             \
    const int e_  = (stp) >> 3;                                               \
    const int kc_ = ((stp) & 7) << 6;                                         \
    const int kh_ = (e_ * 11) >> 5;                                           \
    const int kw_ = e_ - kh_ * 3;                                             \
    const unsigned short* Ab_ = wt + (size_t)e_ * (COUT * CIN)                \
                                   + (size_t)m0 * 512 + kc_;                  \
    const unsigned short* Bb_ = xpad + bImgBase                               \
                              + (size_t)((h0 + kh_) * PAD_IMG + kw_) * 512    \
                              + kc_;                                          \
    gload16(Ab_ + aD0, (AT) + aL0);                                           \
    gload16(Ab_ + aD1, (AT) + aL1);                                           \
    gload16(Bb_ + bD0, (BT) + bL0);                                           \
    gload16(Bb_ + bD1, (BT) + bL1);                                           \
    gload16(Bb_ + bD2, (BT) + bL2);                                           \
    gload16(Bb_ + bD3, (BT) + bL3);                                           \
} while (0)

#define MFMA4(ni, bc)                                                         \
    acc[0][ni] = __builtin_amdgcn_mfma_f32_16x16x32_bf16(af0, bc, acc[0][ni], 0, 0, 0); \
    acc[1][ni] = __builtin_amdgcn_mfma_f32_16x16x32_bf16(af1, bc, acc[1][ni], 0, 0, 0); \
    acc[2][ni] = __builtin_amdgcn_mfma_f32_16x16x32_bf16(af2, bc, acc[2][ni], 0, 0, 0); \
    acc[3][ni] = __builtin_amdgcn_mfma_f32_16x16x32_bf16(af3, bc, acc[3][ni], 0, 0, 0)

#define PIN_R() __builtin_amdgcn_sched_group_barrier(0x100, 1, 0)
#define PIN_M() __builtin_amdgcn_sched_group_barrier(0x008, 4, 0)

__global__ __launch_bounds__(512, 2) void conv_mfma(
    const unsigned short* __restrict__ wt,    // [9][512][512] bf16
    const unsigned short* __restrict__ xpad,  // [16][34][34][512] bf16
    const float* __restrict__ scl,            // [16][512]
    float* __restrict__ out)                  // [16][512][32][32]
{
    // 96KB carved: A dbuf 2x16KB, B dbuf 2x32KB; epilogue reuses as f32.
    __shared__ __align__(16) unsigned char smem[98304];
    unsigned short* Alds0 = (unsigned short*)(smem);
    unsigned short* Alds1 = (unsigned short*)(smem + 16384);
    unsigned short* Blds0 = (unsigned short*)(smem + 32768);
    unsigned short* Blds1 = (unsigned short*)(smem + 65536);
    __shared__ float sclds[128];

    const int tid = threadIdx.x;
    // XCD swizzle: 256 blocks, id&7 -> XCD. Per XCD: 8 N-blocks x 4 m.
    const int id    = blockIdx.x;
    const int xcd   = id & 7;
    const int local = id >> 3;                   // 0..31
    const int gp    = xcd * 8 + (local >> 2);    // 0..63  N-block (b, hg)
    const int m0  = (local & 3) * 128;
    const int b   = gp >> 2;                     // 0..15
    const int h0  = (gp & 3) * 8;                // 0,8,16,24

    if (tid < 128) sclds[tid] = scl[b * 512 + m0 + tid];

    const int wid  = tid >> 6;
    const int lane = tid & 63;
    const int wm = (wid >> 1) & 1;               // M half (64 rows)
    const int wn = wid & 1;                      // N half (128 px)
    const int kg = wid >> 2;                     // k-group (k-half of step)

    const f32x4 vzero = {0.f, 0.f, 0.f, 0.f};
    f32x4 acc[4][8];
    #pragma unroll
    for (int i = 0; i < 4; ++i)
        #pragma unroll
        for (int j = 0; j < 8; ++j) acc[i][j] = vzero;

    // DMA addressing. LDS stays LINEAR in (row, slot): DMA writes
    // wave-uniform base + lane*16B = row (base+l>>3), slot (l&7).
    // Swizzle moved to the SOURCE: slot p holds logical chunk
    // c = p ^ (row&7) = (l&7)^(l>>3)  (bases are %8==0). Same 128B
    // segment per 8-lane group -> coalescing intact. (rule #21)
    int aD0, aD1, bD0, bD1, bD2, bD3;            // per-lane global offsets
    int aL0, aL1, bL0, bL1, bL2, bL3;            // wave-uniform LDS offsets
    {
        const int l3 = lane >> 3;                // 0..7 (row within instr)
        const int cD = ((lane & 7) ^ l3) * 8;    // pre-swizzled chunk
        const int ra = wid * 16 + l3;            // A row, instr 0
        aD0 = ra * 512 + cD;
        aD1 = aD0 + 8 * 512;                     // instr 1: +8 rows
        aL0 = (wid * 16) * 64;
        aL1 = (wid * 16 + 8) * 64;
        int rb = wid * 32 + l3;                  // B px row, instr 0..3
        bD0 = ((rb >> 5) * PAD_IMG + (rb & 31)) * 512 + cD;  rb += 8;
        bD1 = ((rb >> 5) * PAD_IMG + (rb & 31)) * 512 + cD;  rb += 8;
        bD2 = ((rb >> 5) * PAD_IMG + (rb & 31)) * 512 + cD;  rb += 8;
        bD3 = ((rb >> 5) * PAD_IMG + (rb & 31)) * 512 + cD;
        bL0 = (wid * 32 +  0) * 64;
        bL1 = (wid * 32 +  8) * 64;
        bL2 = (wid * 32 + 16) * 64;
        bL3 = (wid * 32 + 24) * 64;
    }

    const size_t bImgBase = (size_t)b * PAD_IMG * PAD_IMG * 512;

    // fragment read addresses: wave reads k-chunk q = kg*4+kch at
    // swizzled position q^(row&7); row&7 = rl&7 (wave bases %16==0).
    const int rl   = lane & 15;
    const int kch  = lane >> 4;                  // 0..3
    const int swz  = ((kg * 4 + kch) ^ (rl & 7)) * 8;
    const int arow = (wm * 64 + rl) * 64;
    const int brow = (wn * 128 + rl) * 64;

    // prologue: DMA step 0 into buf0, drain, publish.
    DMASTEP(0, Alds0, Blds0);
    SYNC();

    for (int step = 0; step < 72; ++step) {
        unsigned short* Ac = (step & 1) ? Alds1 : Alds0;
        unsigned short* Bc = (step & 1) ? Blds1 : Blds0;
        unsigned short* An = (step & 1) ? Alds0 : Alds1;
        unsigned short* Bn = (step & 1) ? Blds0 : Blds1;
        const int nxt = step + 1 < 72 ? step + 1 : 71;
        // issue next step's DMA into buf^1 (its last readers drained
        // before the barrier we just crossed); lands during this phase.
        DMASTEP(nxt, An, Bn);
        __builtin_amdgcn_sched_group_barrier(0x020, 6, 0);  // 6 VMEM_READ

        // reads + MFMA, R20 interleave: {5 DS_READ} + 7x{1 R, 4 MFMA} +
        // {4 MFMA}. Each group starts once ITS operand landed.
        bf16x8 af0, af1, af2, af3, bf0, bf1, bf2, bf3, bf4, bf5, bf6, bf7;
        af0 = *(const bf16x8*)(Ac + arow + 0 * 1024 + swz);
        af1 = *(const bf16x8*)(Ac + arow + 1 * 1024 + swz);
        af2 = *(const bf16x8*)(Ac + arow + 2 * 1024 + swz);
        af3 = *(const bf16x8*)(Ac + arow + 3 * 1024 + swz);
        bf0 = *(const bf16x8*)(Bc + brow + 0 * 1024 + swz);
        __builtin_amdgcn_sched_group_barrier(0x100, 5, 0);
        __builtin_amdgcn_s_setprio(1);
        bf1 = *(const bf16x8*)(Bc + brow + 1 * 1024 + swz);
        MFMA4(0, bf0); PIN_R(); PIN_M();
        bf2 = *(const bf16x8*)(Bc + brow + 2 * 1024 + swz);
        MFMA4(1, bf1); PIN_R(); PIN_M();
        bf3 = *(const bf16x8*)(Bc + brow + 3 * 1024 + swz);
        MFMA4(2, bf2); PIN_R(); PIN_M();
        bf4 = *(const bf16x8*)(Bc + brow + 4 * 1024 + swz);
        MFMA4(3, bf3); PIN_R(); PIN_M();
        bf5 = *(const bf16x8*)(Bc + brow + 5 * 1024 + swz);
        MFMA4(4, bf4); PIN_R(); PIN_M();
        bf6 = *(const bf16x8*)(Bc + brow + 6 * 1024 + swz);
        MFMA4(5, bf5); PIN_R(); PIN_M();
        bf7 = *(const bf16x8*)(Bc + brow + 7 * 1024 + swz);
        MFMA4(6, bf6); PIN_R(); PIN_M();
        MFMA4(7, bf7); PIN_M();
        __builtin_amdgcn_s_setprio(0);

        // vmcnt(0): this wave's DMAs (issued at phase top, ~2000cy old)
        // complete; lgkm: ds reads done. Barrier publishes buf^1.
        SYNC();
    }

    // ---- epilogue: merge kg partials via LDS, scale, store ----
    // C frag layout: col(N)=lane&15, row(M)=(lane>>4)*4+reg [m89-verified]
    const int colp = lane & 15;
    const int rowq = (lane >> 4) * 4;
    float* ep = (float*)smem;                    // 96KB as f32
    float* reg = ep + wn * 8192;                 // 32KB region per wn
    for (int wmr = 0; wmr < 2; ++wmr) {
        __syncthreads();
        if (wm == wmr && kg == 1) {
            #pragma unroll
            for (int mi = 0; mi < 4; ++mi)
                #pragma unroll
                for (int ni = 0; ni < 8; ++ni)
                    *(f32x4*)(reg + ((mi * 8 + ni) * 64 + lane) * 4) =
                        acc[mi][ni];
        }
        __syncthreads();
        if (wm == wmr && kg == 0) {
            #pragma unroll
            for (int mi = 0; mi < 4; ++mi) {
                #pragma unroll
                for (int ni = 0; ni < 8; ++ni) {
                    const f32x4 o =
                        *(const f32x4*)(reg + ((mi * 8 + ni) * 64 + lane) * 4);
                    const int p = h0 * 32 + wn * 128 + ni * 16 + colp;
                    #pragma unroll
                    for (int r2 = 0; r2 < 4; ++r2) {
                        const int ol = wm * 64 + mi * 16 + rowq + r2;
                        out[(((size_t)b * 512 + m0 + ol) << 10) + p] =
                            (acc[mi][ni][r2] + o[r2]) * sclds[ol];
                    }
                }
            }
        }
    }
}

extern "C" void kernel_launch(void* const* d_in, const int* in_sizes, int n_in,
                              void* d_out, int out_size, void* d_ws, size_t ws_size,
                              hipStream_t stream) {
    const float* x     = (const float*)d_in[0];  // [16,512,32,32]
    const float* style = (const float*)d_in[1];  // [16,512]
    const float* aw    = (const float*)d_in[2];  // [512,512]
    const float* ab    = (const float*)d_in[3];  // [512]
    const float* cw    = (const float*)d_in[4];  // [512,512,3,3]
    float* out = (float*)d_out;

    char* ws = (char*)d_ws;
    float* s_buf          = (float*)(ws);                      //  32 KB
    float* scl            = (float*)(ws + 32768);              //  32 KB
    float* wsq            = (float*)(ws + 65536);              //   1 MB
    unsigned short* w_t   = (unsigned short*)(ws + 1114112);   // 4.5 MB bf16
    unsigned short* x_pad = (unsigned short*)(ws + 5832704);   // 18.9 MB bf16
    // total ws need: 24,772,608 B

    prep1<<<dim3(2560), 256, 0, stream>>>(cw, style, aw, ab, w_t, wsq, s_buf);
    prep2<<<dim3(6400), 256, 0, stream>>>(x, s_buf, wsq, x_pad, scl);
    conv_mfma<<<dim3(256), 512, 0, stream>>>(w_t, x_pad, scl, out);
}